// Round 1
// baseline (789.415 us; speedup 1.0000x reference)
//
#include <hip/hip_runtime.h>
#include <stdint.h>

#define B_ROWS 8192
#define K_DIM 2048
#define N_DIM 2048
#define NPOP 8

typedef float f32x4 __attribute__((ext_vector_type(4)));
typedef __bf16 bf16x8 __attribute__((ext_vector_type(8)));

__device__ __forceinline__ unsigned short f2bf(float f) {
  unsigned int u = __float_as_uint(f);
  u += 0x7fffu + ((u >> 16) & 1u);   // round-to-nearest-even (normals; inputs are finite)
  return (unsigned short)(u >> 16);
}

// async global->LDS, 16B per lane; LDS side = wave-uniform base + lane*16
__device__ __forceinline__ void glds16(const unsigned short* g, unsigned short* l) {
  __builtin_amdgcn_global_load_lds(
      (__attribute__((address_space(1))) unsigned int*)g,
      (__attribute__((address_space(3))) unsigned int*)l, 16, 0, 0);
}

// ---- W fp32 -> bf16 ----
__global__ void prep_w_kernel(const float* __restrict__ W, unsigned short* __restrict__ Wb) {
  const int n4 = NPOP * N_DIM * K_DIM / 4;
  int stride = gridDim.x * blockDim.x;
  for (int i = blockIdx.x * blockDim.x + threadIdx.x; i < n4; i += stride) {
    float4 v = reinterpret_cast<const float4*>(W)[i];
    ushort4 s;
    s.x = f2bf(v.x); s.y = f2bf(v.y); s.z = f2bf(v.z); s.w = f2bf(v.w);
    reinterpret_cast<ushort4*>(Wb)[i] = s;
  }
}

// ---- x fp32 -> bf16, selector logits (fp32), top-2 routing ----
// one wave per row; lists[lid*2048 + pos], lid = slot*8 + expert
__global__ void prep_x_sel_kernel(const float* __restrict__ x,
                                  const float* __restrict__ Ws,
                                  const float* __restrict__ bs,
                                  unsigned short* __restrict__ xb,
                                  int* __restrict__ lists,
                                  int* __restrict__ cnt) {
  const int w = threadIdx.x >> 6;
  const int l = threadIdx.x & 63;
  const int r = blockIdx.x * 4 + w;   // grid 2048*4 = 8192 rows exactly

  float acc[NPOP];
#pragma unroll
  for (int p = 0; p < NPOP; ++p) acc[p] = 0.f;

  const float4* x4  = reinterpret_cast<const float4*>(x);
  const float4* Ws4 = reinterpret_cast<const float4*>(Ws);
#pragma unroll
  for (int j = 0; j < 8; ++j) {
    int idx = j * 256 + l * 4;
    float4 v = x4[(r * K_DIM + idx) >> 2];
    ushort4 s; s.x = f2bf(v.x); s.y = f2bf(v.y); s.z = f2bf(v.z); s.w = f2bf(v.w);
    *reinterpret_cast<ushort4*>(xb + (size_t)r * K_DIM + idx) = s;
#pragma unroll
    for (int p = 0; p < NPOP; ++p) {
      float4 wv = Ws4[(p * K_DIM + idx) >> 2];
      acc[p] += v.x * wv.x + v.y * wv.y + v.z * wv.z + v.w * wv.w;
    }
  }
  // 64-lane butterfly reduce, all 8 logits
#pragma unroll
  for (int off = 32; off > 0; off >>= 1)
#pragma unroll
    for (int p = 0; p < NPOP; ++p) acc[p] += __shfl_xor(acc[p], off, 64);

  if (l == 0) {
    float lg[NPOP];
#pragma unroll
    for (int p = 0; p < NPOP; ++p) lg[p] = acc[p] + bs[p];
    int p1 = 0;
#pragma unroll
    for (int p = 1; p < NPOP; ++p) if (lg[p] > lg[p1]) p1 = p;   // strict > : low index wins ties
    int p2 = -1;
#pragma unroll
    for (int p = 0; p < NPOP; ++p) {
      if (p == p1) continue;
      if (p2 < 0 || lg[p] > lg[p2]) p2 = p;
    }
    int pos1 = atomicAdd(&cnt[p1], 1);
    if (pos1 < 2048) lists[p1 * 2048 + pos1] = r;
    int pos2 = atomicAdd(&cnt[8 + p2], 1);
    if (pos2 < 2048) lists[(8 + p2) * 2048 + pos2] = r;
  }
}

// ---- grouped GEMM, 128x128 tile, BK=32, mfma_f32_16x16x32_bf16 (m97 structure) ----
// pass 0: out = 0.5*(X Wp^T + b[p]) for slot-0 rows; pass 1: out += same for slot-1 rows.
__global__ __launch_bounds__(256) void gemm_kernel(
    const unsigned short* __restrict__ xb,
    const unsigned short* __restrict__ Wb,
    const float* __restrict__ bvec,
    const int* __restrict__ lists,
    const int* __restrict__ cnt,
    float* __restrict__ out,
    int pass) {
  const int g   = blockIdx.z;
  const int lid = pass * 8 + g;
  const int cg  = cnt[lid];
  const int m0  = blockIdx.x * 128;
  if (m0 >= cg) return;
  const int n0 = blockIdx.y * 128;

  __shared__ __align__(16) unsigned short As[128 * 32];
  __shared__ __align__(16) unsigned short Bs[128 * 32];
  __shared__ int   sh_rows[128];
  __shared__ float sh_bias[128];

  const int t = threadIdx.x;
  const int w = t >> 6;     // wave 0..3
  const int l = t & 63;

  const int* list = lists + lid * 2048;
  if (t < 128) {
    int idx = m0 + t;
    sh_rows[t] = (idx < cg) ? list[idx] : -1;
    sh_bias[t] = bvec[g * N_DIM + n0 + t];
  }
  __syncthreads();

  int ar0 = sh_rows[32 * w + (l >> 2)];      if (ar0 < 0) ar0 = 0;  // clamp pad rows
  int ar1 = sh_rows[32 * w + 16 + (l >> 2)]; if (ar1 < 0) ar1 = 0;
  const unsigned short* ap0 = xb + (size_t)ar0 * K_DIM + (l & 3) * 8;
  const unsigned short* ap1 = xb + (size_t)ar1 * K_DIM + (l & 3) * 8;
  const unsigned short* wbase = Wb + (size_t)g * N_DIM * K_DIM;
  const unsigned short* bp0 = wbase + (size_t)(n0 + 32 * w + (l >> 2)) * K_DIM + (l & 3) * 8;
  const unsigned short* bp1 = bp0 + (size_t)16 * K_DIM;

  unsigned short* As_w0 = As + (2 * w)     * 512;  // wave-uniform LDS bases
  unsigned short* As_w1 = As + (2 * w + 1) * 512;
  unsigned short* Bs_w0 = Bs + (2 * w)     * 512;
  unsigned short* Bs_w1 = Bs + (2 * w + 1) * 512;

  const int wm = w >> 1, wn = w & 1;
  const int lane16 = l & 15;   // A: m-index, B: n-index, C/D: col
  const int quad   = l >> 4;   // k-chunk / C-row quad

  f32x4 acc[4][4];
#pragma unroll
  for (int i = 0; i < 4; ++i)
#pragma unroll
    for (int j = 0; j < 4; ++j) { f32x4 z = {0.f, 0.f, 0.f, 0.f}; acc[i][j] = z; }

  for (int k0 = 0; k0 < K_DIM; k0 += 32) {
    glds16(ap0 + k0, As_w0);
    glds16(ap1 + k0, As_w1);
    glds16(bp0 + k0, Bs_w0);
    glds16(bp1 + k0, Bs_w1);
    __syncthreads();   // compiler drains vmcnt(0) before s_barrier

    bf16x8 af[4], bf[4];
#pragma unroll
    for (int mi = 0; mi < 4; ++mi)
      af[mi] = *reinterpret_cast<const bf16x8*>(&As[(wm * 64 + mi * 16 + lane16) * 32 + quad * 8]);
#pragma unroll
    for (int ni = 0; ni < 4; ++ni)
      bf[ni] = *reinterpret_cast<const bf16x8*>(&Bs[(wn * 64 + ni * 16 + lane16) * 32 + quad * 8]);
#pragma unroll
    for (int mi = 0; mi < 4; ++mi)
#pragma unroll
      for (int ni = 0; ni < 4; ++ni)
        acc[mi][ni] = __builtin_amdgcn_mfma_f32_16x16x32_bf16(af[mi], bf[ni], acc[mi][ni], 0, 0, 0);
    __syncthreads();   // WAR: LDS reuse next iter
  }

  // epilogue: C/D layout col=lane&15, row=quad*4+reg (m89/m91-verified)
#pragma unroll
  for (int mi = 0; mi < 4; ++mi) {
#pragma unroll
    for (int i = 0; i < 4; ++i) {
      int crow = wm * 64 + mi * 16 + quad * 4 + i;
      int r = sh_rows[crow];
      if (r < 0) continue;
      float* orow = out + (size_t)r * N_DIM + n0;
#pragma unroll
      for (int ni = 0; ni < 4; ++ni) {
        int colL = wn * 64 + ni * 16 + lane16;
        float v = 0.5f * acc[mi][ni][i] + 0.5f * sh_bias[colL];
        if (pass == 0) orow[colL] = v;
        else           orow[colL] += v;
      }
    }
  }
}

extern "C" void kernel_launch(void* const* d_in, const int* in_sizes, int n_in,
                              void* d_out, int out_size, void* d_ws, size_t ws_size,
                              hipStream_t stream) {
  const float* x  = (const float*)d_in[0];
  const float* W  = (const float*)d_in[1];
  const float* b  = (const float*)d_in[2];
  const float* Ws = (const float*)d_in[3];
  const float* bs = (const float*)d_in[4];
  float* out = (float*)d_out;

  // workspace: Wb bf16 (64MiB) | xb bf16 (32MiB) | lists 16*2048 int | cnt 16 int
  char* ws = (char*)d_ws;
  unsigned short* Wb = (unsigned short*)ws;
  unsigned short* xb = (unsigned short*)(ws + (size_t)67108864);
  int* lists = (int*)(ws + (size_t)67108864 + 33554432);
  int* cnt   = (int*)(ws + (size_t)67108864 + 33554432 + 131072);

  hipMemsetAsync(cnt, 0, 16 * sizeof(int), stream);
  prep_w_kernel<<<4096, 256, 0, stream>>>(W, Wb);
  prep_x_sel_kernel<<<2048, 256, 0, stream>>>(x, Ws, bs, xb, lists, cnt);
  gemm_kernel<<<dim3(16, 16, 8), 256, 0, stream>>>(xb, Wb, b, lists, cnt, out, 0);
  gemm_kernel<<<dim3(16, 16, 8), 256, 0, stream>>>(xb, Wb, b, lists, cnt, out, 1);
}

// Round 2
// 641.819 us; speedup vs baseline: 1.2300x; 1.2300x over previous
//
#include <hip/hip_runtime.h>
#include <stdint.h>

#define B_ROWS 8192
#define K_DIM 2048
#define N_DIM 2048
#define NPOP 8

typedef float f32x4 __attribute__((ext_vector_type(4)));
typedef __bf16 bf16x8 __attribute__((ext_vector_type(8)));

__device__ __forceinline__ unsigned short f2bf(float f) {
  unsigned int u = __float_as_uint(f);
  u += 0x7fffu + ((u >> 16) & 1u);   // round-to-nearest-even
  return (unsigned short)(u >> 16);
}

// async global->LDS, 16B per lane; LDS side = wave-uniform base + lane*16
__device__ __forceinline__ void glds16(const unsigned short* g, unsigned short* l) {
  __builtin_amdgcn_global_load_lds(
      (__attribute__((address_space(1))) unsigned int*)g,
      (__attribute__((address_space(3))) unsigned int*)l, 16, 0, 0);
}

// ---- W fp32 -> bf16 ----
__global__ void prep_w_kernel(const float* __restrict__ W, unsigned short* __restrict__ Wb) {
  const int n4 = NPOP * N_DIM * K_DIM / 4;
  int stride = gridDim.x * blockDim.x;
  for (int i = blockIdx.x * blockDim.x + threadIdx.x; i < n4; i += stride) {
    float4 v = reinterpret_cast<const float4*>(W)[i];
    ushort4 s;
    s.x = f2bf(v.x); s.y = f2bf(v.y); s.z = f2bf(v.z); s.w = f2bf(v.w);
    reinterpret_cast<ushort4*>(Wb)[i] = s;
  }
}

// ---- x fp32 -> bf16, selector logits (fp32), top-2 -> sel[row] (NO atomics) ----
__global__ void prep_x_sel_kernel(const float* __restrict__ x,
                                  const float* __restrict__ Ws,
                                  const float* __restrict__ bs,
                                  unsigned short* __restrict__ xb,
                                  int* __restrict__ sel) {
  const int w = threadIdx.x >> 6;
  const int l = threadIdx.x & 63;
  const int r = blockIdx.x * 4 + w;   // 2048 blocks * 4 waves = 8192 rows

  float acc[NPOP];
#pragma unroll
  for (int p = 0; p < NPOP; ++p) acc[p] = 0.f;

  const float4* x4  = reinterpret_cast<const float4*>(x);
  const float4* Ws4 = reinterpret_cast<const float4*>(Ws);
#pragma unroll
  for (int j = 0; j < 8; ++j) {
    int idx = j * 256 + l * 4;
    float4 v = x4[(r * K_DIM + idx) >> 2];
    ushort4 s; s.x = f2bf(v.x); s.y = f2bf(v.y); s.z = f2bf(v.z); s.w = f2bf(v.w);
    *reinterpret_cast<ushort4*>(xb + (size_t)r * K_DIM + idx) = s;
#pragma unroll
    for (int p = 0; p < NPOP; ++p) {
      float4 wv = Ws4[(p * K_DIM + idx) >> 2];
      acc[p] += v.x * wv.x + v.y * wv.y + v.z * wv.z + v.w * wv.w;
    }
  }
#pragma unroll
  for (int off = 32; off > 0; off >>= 1)
#pragma unroll
    for (int p = 0; p < NPOP; ++p) acc[p] += __shfl_xor(acc[p], off, 64);

  if (l == 0) {
    float lg[NPOP];
#pragma unroll
    for (int p = 0; p < NPOP; ++p) lg[p] = acc[p] + bs[p];
    int p1 = 0;
#pragma unroll
    for (int p = 1; p < NPOP; ++p) if (lg[p] > lg[p1]) p1 = p;   // strict >: low index wins ties
    int p2 = -1;
#pragma unroll
    for (int p = 0; p < NPOP; ++p) {
      if (p == p1) continue;
      if (p2 < 0 || lg[p] > lg[p2]) p2 = p;
    }
    sel[r] = p1 * 8 + p2;
  }
}

// ---- build per-(slot,expert) row lists deterministically (one block per list) ----
__global__ __launch_bounds__(256) void build_lists_kernel(const int* __restrict__ sel,
                                                          int* __restrict__ lists,
                                                          int* __restrict__ cnt) {
  const int lid  = blockIdx.x;      // 0..15
  const int slot = lid >> 3;
  const int ex   = lid & 7;
  const int t    = threadIdx.x;

  __shared__ int psum[256];

  int local[32];
  int c = 0;
#pragma unroll
  for (int i = 0; i < 32; ++i) {
    int r = i * 256 + t;            // coalesced scan
    int s = sel[r];
    int e = slot ? (s & 7) : (s >> 3);
    if (e == ex) local[c++] = r;
  }
  psum[t] = c;
  __syncthreads();
  for (int off = 1; off < 256; off <<= 1) {   // Hillis-Steele inclusive scan
    int v = (t >= off) ? psum[t - off] : 0;
    __syncthreads();
    psum[t] += v;
    __syncthreads();
  }
  int start = psum[t] - c;
  for (int i = 0; i < c; ++i) lists[lid * 2048 + start + i] = local[i];
  if (t == 255) cnt[lid] = psum[255];
}

// ---- grouped GEMM, 128x128 tile, BK=32, mfma_f32_16x16x32_bf16 (m97 structure) ----
__global__ __launch_bounds__(256) void gemm_kernel(
    const unsigned short* __restrict__ xb,
    const unsigned short* __restrict__ Wb,
    const float* __restrict__ bvec,
    const int* __restrict__ lists,
    const int* __restrict__ cnt,
    float* __restrict__ out,
    int pass) {
  const int g   = blockIdx.z;
  const int lid = pass * 8 + g;
  const int cg  = cnt[lid];
  const int m0  = blockIdx.x * 128;
  if (m0 >= cg) return;
  const int n0 = blockIdx.y * 128;

  __shared__ __align__(16) unsigned short As[128 * 32];
  __shared__ __align__(16) unsigned short Bs[128 * 32];
  __shared__ int   sh_rows[128];
  __shared__ float sh_bias[128];

  const int t = threadIdx.x;
  const int w = t >> 6;
  const int l = t & 63;

  const int* list = lists + lid * 2048;
  if (t < 128) {
    int idx = m0 + t;
    sh_rows[t] = (idx < cg) ? list[idx] : -1;
    sh_bias[t] = bvec[g * N_DIM + n0 + t];
  }
  __syncthreads();

  int ar0 = sh_rows[32 * w + (l >> 2)];      if (ar0 < 0) ar0 = 0;
  int ar1 = sh_rows[32 * w + 16 + (l >> 2)]; if (ar1 < 0) ar1 = 0;
  const unsigned short* ap0 = xb + (size_t)ar0 * K_DIM + (l & 3) * 8;
  const unsigned short* ap1 = xb + (size_t)ar1 * K_DIM + (l & 3) * 8;
  const unsigned short* wbase = Wb + (size_t)g * N_DIM * K_DIM;
  const unsigned short* bp0 = wbase + (size_t)(n0 + 32 * w + (l >> 2)) * K_DIM + (l & 3) * 8;
  const unsigned short* bp1 = bp0 + (size_t)16 * K_DIM;

  unsigned short* As_w0 = As + (2 * w)     * 512;
  unsigned short* As_w1 = As + (2 * w + 1) * 512;
  unsigned short* Bs_w0 = Bs + (2 * w)     * 512;
  unsigned short* Bs_w1 = Bs + (2 * w + 1) * 512;

  const int wm = w >> 1, wn = w & 1;
  const int lane16 = l & 15;
  const int quad   = l >> 4;

  f32x4 acc[4][4];
#pragma unroll
  for (int i = 0; i < 4; ++i)
#pragma unroll
    for (int j = 0; j < 4; ++j) { f32x4 z = {0.f, 0.f, 0.f, 0.f}; acc[i][j] = z; }

  for (int k0 = 0; k0 < K_DIM; k0 += 32) {
    glds16(ap0 + k0, As_w0);
    glds16(ap1 + k0, As_w1);
    glds16(bp0 + k0, Bs_w0);
    glds16(bp1 + k0, Bs_w1);
    __syncthreads();

    bf16x8 af[4], bf[4];
#pragma unroll
    for (int mi = 0; mi < 4; ++mi)
      af[mi] = *reinterpret_cast<const bf16x8*>(&As[(wm * 64 + mi * 16 + lane16) * 32 + quad * 8]);
#pragma unroll
    for (int ni = 0; ni < 4; ++ni)
      bf[ni] = *reinterpret_cast<const bf16x8*>(&Bs[(wn * 64 + ni * 16 + lane16) * 32 + quad * 8]);
#pragma unroll
    for (int mi = 0; mi < 4; ++mi)
#pragma unroll
      for (int ni = 0; ni < 4; ++ni)
        acc[mi][ni] = __builtin_amdgcn_mfma_f32_16x16x32_bf16(af[mi], bf[ni], acc[mi][ni], 0, 0, 0);
    __syncthreads();
  }

#pragma unroll
  for (int mi = 0; mi < 4; ++mi) {
#pragma unroll
    for (int i = 0; i < 4; ++i) {
      int crow = wm * 64 + mi * 16 + quad * 4 + i;
      int r = sh_rows[crow];
      if (r < 0) continue;
      float* orow = out + (size_t)r * N_DIM + n0;
#pragma unroll
      for (int ni = 0; ni < 4; ++ni) {
        int colL = wn * 64 + ni * 16 + lane16;
        float v = 0.5f * acc[mi][ni][i] + 0.5f * sh_bias[colL];
        if (pass == 0) orow[colL] = v;
        else           orow[colL] += v;
      }
    }
  }
}

extern "C" void kernel_launch(void* const* d_in, const int* in_sizes, int n_in,
                              void* d_out, int out_size, void* d_ws, size_t ws_size,
                              hipStream_t stream) {
  const float* x  = (const float*)d_in[0];
  const float* W  = (const float*)d_in[1];
  const float* b  = (const float*)d_in[2];
  const float* Ws = (const float*)d_in[3];
  const float* bs = (const float*)d_in[4];
  float* out = (float*)d_out;

  // ws: Wb bf16 (64MiB) | xb bf16 (32MiB) | lists 16*2048 int | cnt 16 int | sel 8192 int
  char* ws = (char*)d_ws;
  unsigned short* Wb = (unsigned short*)ws;
  unsigned short* xb = (unsigned short*)(ws + (size_t)67108864);
  int* lists = (int*)(ws + (size_t)67108864 + 33554432);
  int* cnt   = (int*)(ws + (size_t)67108864 + 33554432 + 131072);
  int* sel   = (int*)(ws + (size_t)67108864 + 33554432 + 131072 + 4096);

  prep_w_kernel<<<4096, 256, 0, stream>>>(W, Wb);
  prep_x_sel_kernel<<<2048, 256, 0, stream>>>(x, Ws, bs, xb, sel);
  build_lists_kernel<<<16, 256, 0, stream>>>(sel, lists, cnt);
  gemm_kernel<<<dim3(16, 16, 8), 256, 0, stream>>>(xb, Wb, b, lists, cnt, out, 0);
  gemm_kernel<<<dim3(16, 16, 8), 256, 0, stream>>>(xb, Wb, b, lists, cnt, out, 1);
}